// Round 1
// baseline (884.873 us; speedup 1.0000x reference)
//
#include <hip/hip_runtime.h>
#include <climits>
#include <cstdint>

// Round 1: correct implementation.
// ws layout:
//   [0] float coarse_sum   (atomicAdd target)
//   [1] float fine_sum
//   [2] int   fine_cnt
//   [3] int   valid_cnt
//   [4...]   int jv[B*L]  (first j with gt>0, or -1)   @ byte offset 16

__global__ __launch_bounds__(256) void mc_coarse_kernel(
    const float* __restrict__ cm, const float* __restrict__ gt, int L,
    float* __restrict__ coarse_sum, int* __restrict__ jv,
    int* __restrict__ valid_cnt)
{
    const int row = blockIdx.x;                 // row = b*L + i
    const size_t off = (size_t)row * L;
    const float4* __restrict__ g4 = reinterpret_cast<const float4*>(gt + off);
    const float* __restrict__ c  = cm + off;

    float local = 0.0f;       // sum of gt * log(cm + 1e-6) (negated at end)
    int   minj  = INT_MAX;    // first j with gt > 0

    const int nvec = L >> 2;
    for (int v = threadIdx.x; v < nvec; v += blockDim.x) {
        float4 gv = g4[v];
        int j = v << 2;
        if (gv.x != 0.0f) { local += gv.x * logf(c[j + 0] + 1e-6f); if (gv.x > 0.0f) minj = min(minj, j + 0); }
        if (gv.y != 0.0f) { local += gv.y * logf(c[j + 1] + 1e-6f); if (gv.y > 0.0f) minj = min(minj, j + 1); }
        if (gv.z != 0.0f) { local += gv.z * logf(c[j + 2] + 1e-6f); if (gv.z > 0.0f) minj = min(minj, j + 2); }
        if (gv.w != 0.0f) { local += gv.w * logf(c[j + 3] + 1e-6f); if (gv.w > 0.0f) minj = min(minj, j + 3); }
    }

    // wave (64-lane) reduction
    #pragma unroll
    for (int o = 32; o; o >>= 1) {
        local += __shfl_down(local, o);
        minj = min(minj, __shfl_down(minj, o));
    }
    __shared__ float ssum[4];
    __shared__ int   smin[4];
    const int wid = threadIdx.x >> 6, lane = threadIdx.x & 63;
    if (lane == 0) { ssum[wid] = local; smin[wid] = minj; }
    __syncthreads();
    if (threadIdx.x == 0) {
        float t = 0.0f; int m = INT_MAX;
        const int nw = blockDim.x >> 6;
        for (int w = 0; w < nw; ++w) { t += ssum[w]; m = min(m, smin[w]); }
        atomicAdd(coarse_sum, -t);
        jv[row] = (m == INT_MAX) ? -1 : m;
        if (m != INT_MAX) atomicAdd(valid_cnt, 1);
    }
}

__global__ __launch_bounds__(64) void mc_fine_kernel(
    const float* __restrict__ s0, const float* __restrict__ s1,
    const float* __restrict__ mk0, const float* __restrict__ mk1,
    const int* __restrict__ jv, int B, int L,
    float* __restrict__ fine_sum, int* __restrict__ fine_cnt)
{
    const int n = blockIdx.x;
    const float bf = mk0[3 * n + 0];
    const float x  = mk0[3 * n + 1];
    const float y  = mk0[3 * n + 2];
    const int b = (int)bf;

    int best = INT_MAX;
    if ((float)b == bf && b >= 0 && b < B) {
        const float* __restrict__ srow = s0 + (size_t)b * L * 2;
        const int*   __restrict__ jrow = jv + (size_t)b * L;
        for (int i = threadIdx.x; i < L; i += 64) {
            if (jrow[i] >= 0) {
                float sx = srow[2 * i + 0];
                float sy = srow[2 * i + 1];
                if (sx == x && sy == y) best = min(best, i);
            }
        }
    }
    #pragma unroll
    for (int o = 32; o; o >>= 1) best = min(best, __shfl_down(best, o));

    if (threadIdx.x == 0 && best != INT_MAX) {
        const int j = jv[(size_t)b * L + best];
        const float gx = s1[((size_t)b * L + j) * 2 + 0];
        const float gy = s1[((size_t)b * L + j) * 2 + 1];
        const float dx = gx - mk1[2 * n + 0];
        const float dy = gy - mk1[2 * n + 1];
        const float pn = sqrtf(dx * dx + dy * dy);
        if (pn < 10.0f) {
            atomicAdd(fine_sum, pn);
            atomicAdd(fine_cnt, 1);
        }
    }
}

__global__ void mc_finalize_kernel(const float* __restrict__ wsf,
                                   const int* __restrict__ wsi,
                                   float binv, float* __restrict__ out)
{
    const float coarse = wsf[0] * binv;
    const int cnt  = wsi[2];
    const int vcnt = wsi[3];
    float fine;
    if (vcnt > 0) fine = (cnt > 0) ? (wsf[1] / (float)cnt) : 10.0f;
    else          fine = 1e-6f;
    out[0] = coarse + 1000.0f * fine;
    out[1] = coarse;
    out[2] = fine;
}

extern "C" void kernel_launch(void* const* d_in, const int* in_sizes, int n_in,
                              void* d_out, int out_size, void* d_ws, size_t ws_size,
                              hipStream_t stream) {
    const float* cm  = (const float*)d_in[0];  // [B,L,L]
    const float* gt  = (const float*)d_in[1];  // [B,L,L]
    const float* s0  = (const float*)d_in[2];  // [B,L,2]
    const float* s1  = (const float*)d_in[3];  // [B,L,2]
    const float* mk0 = (const float*)d_in[4];  // [N,3]
    const float* mk1 = (const float*)d_in[5];  // [N,2]
    float* out = (float*)d_out;

    // Derive dims: in_sizes[0] = B*L*L, in_sizes[2] = B*L*2 -> ratio = L/2
    const int L = 2 * (in_sizes[0] / in_sizes[2]);
    const int B = in_sizes[2] / (2 * L);
    const int N = in_sizes[4] / 3;

    float* wsf = (float*)d_ws;
    int*   wsi = (int*)d_ws;
    int*   jv  = (int*)((char*)d_ws + 16);

    // zero the 4 scalar accumulators (async, capture-safe)
    hipMemsetAsync(d_ws, 0, 16, stream);

    mc_coarse_kernel<<<B * L, 256, 0, stream>>>(cm, gt, L, wsf, jv, wsi + 3);
    mc_fine_kernel<<<N, 64, 0, stream>>>(s0, s1, mk0, mk1, jv, B, L, wsf + 1, wsi + 2);
    mc_finalize_kernel<<<1, 1, 0, stream>>>(wsf, wsi, 1.0f / (float)B, out);
}

// Round 2
// 492.451 us; speedup vs baseline: 1.7969x; 1.7969x over previous
//
#include <hip/hip_runtime.h>
#include <climits>
#include <cstdint>

// Round 2: atomic-free restructure.
// R1 post-mortem: 32K same-cache-line device-scope atomics serialized the
// coarse kernel (410 us with every pipe idle). All reductions now go through
// per-row/per-point ws slots + one finalize kernel.
//
// ws layout (bytes):
//   [0,            64K)  float partial[B*L]  per-row sum of gt*log(cm+1e-6)
//   [64K,         128K)  int   jv[B*L]       first j with gt>0, or -1
//   [128K,        144K)  float pnbuf[N]      pn if (found && pn<10) else -1

// ---------- coarse: one wave per row, compile-time L for full unroll ----------
template <int L>
__global__ __launch_bounds__(256) void mc_coarse_tpl(
    const float* __restrict__ cm, const float* __restrict__ gt, int nrows,
    float* __restrict__ partial, int* __restrict__ jv)
{
    const int wid  = threadIdx.x >> 6;
    const int lane = threadIdx.x & 63;
    const int row  = blockIdx.x * 4 + wid;
    if (row >= nrows) return;

    const size_t off = (size_t)row * L;
    const float4* __restrict__ g4 = reinterpret_cast<const float4*>(gt + off);
    const float*  __restrict__ c  = cm + off;

    constexpr int NV = L / 4;   // float4s per row
    constexpr int IT = NV / 64; // per-lane loads (16 for L=4096)

    float4 gv[IT];
    #pragma unroll
    for (int k = 0; k < IT; ++k) gv[k] = g4[lane + k * 64];  // 16 loads in flight

    float local = 0.0f;
    int   minj  = INT_MAX;
    #pragma unroll
    for (int k = 0; k < IT; ++k) {
        const int j = (lane + k * 64) << 2;
        const float4 g = gv[k];
        if (g.x != 0.0f) { local += g.x * logf(c[j + 0] + 1e-6f); if (g.x > 0.0f) minj = min(minj, j + 0); }
        if (g.y != 0.0f) { local += g.y * logf(c[j + 1] + 1e-6f); if (g.y > 0.0f) minj = min(minj, j + 1); }
        if (g.z != 0.0f) { local += g.z * logf(c[j + 2] + 1e-6f); if (g.z > 0.0f) minj = min(minj, j + 2); }
        if (g.w != 0.0f) { local += g.w * logf(c[j + 3] + 1e-6f); if (g.w > 0.0f) minj = min(minj, j + 3); }
    }

    #pragma unroll
    for (int o = 32; o; o >>= 1) {
        local += __shfl_down(local, o);
        minj = min(minj, __shfl_down(minj, o));
    }
    if (lane == 0) {
        partial[row] = local;
        jv[row] = (minj == INT_MAX) ? -1 : minj;
    }
}

// generic-L fallback (same structure, runtime loop)
__global__ __launch_bounds__(256) void mc_coarse_gen(
    const float* __restrict__ cm, const float* __restrict__ gt, int L, int nrows,
    float* __restrict__ partial, int* __restrict__ jv)
{
    const int wid  = threadIdx.x >> 6;
    const int lane = threadIdx.x & 63;
    const int row  = blockIdx.x * 4 + wid;
    if (row >= nrows) return;

    const size_t off = (size_t)row * L;
    const float4* __restrict__ g4 = reinterpret_cast<const float4*>(gt + off);
    const float*  __restrict__ c  = cm + off;

    float local = 0.0f;
    int   minj  = INT_MAX;
    const int nvec = L >> 2;
    for (int v = lane; v < nvec; v += 64) {
        const float4 g = g4[v];
        const int j = v << 2;
        if (g.x != 0.0f) { local += g.x * logf(c[j + 0] + 1e-6f); if (g.x > 0.0f) minj = min(minj, j + 0); }
        if (g.y != 0.0f) { local += g.y * logf(c[j + 1] + 1e-6f); if (g.y > 0.0f) minj = min(minj, j + 1); }
        if (g.z != 0.0f) { local += g.z * logf(c[j + 2] + 1e-6f); if (g.z > 0.0f) minj = min(minj, j + 2); }
        if (g.w != 0.0f) { local += g.w * logf(c[j + 3] + 1e-6f); if (g.w > 0.0f) minj = min(minj, j + 3); }
    }

    #pragma unroll
    for (int o = 32; o; o >>= 1) {
        local += __shfl_down(local, o);
        minj = min(minj, __shfl_down(minj, o));
    }
    if (lane == 0) {
        partial[row] = local;
        jv[row] = (minj == INT_MAX) ? -1 : minj;
    }
}

// ---------- fine: one wave per point, result to pnbuf (no atomics) ----------
__global__ __launch_bounds__(64) void mc_fine_kernel(
    const float* __restrict__ s0, const float* __restrict__ s1,
    const float* __restrict__ mk0, const float* __restrict__ mk1,
    const int* __restrict__ jv, int B, int L,
    float* __restrict__ pnbuf)
{
    const int n = blockIdx.x;
    const float bf = mk0[3 * n + 0];
    const float x  = mk0[3 * n + 1];
    const float y  = mk0[3 * n + 2];
    const int b = (int)bf;

    int best = INT_MAX;
    if ((float)b == bf && b >= 0 && b < B) {
        const float2* __restrict__ srow = reinterpret_cast<const float2*>(s0 + (size_t)b * L * 2);
        const int*    __restrict__ jrow = jv + (size_t)b * L;
        #pragma unroll 4
        for (int i = threadIdx.x; i < L; i += 64) {
            const float2 s = srow[i];
            if (s.x == x && s.y == y && jrow[i] >= 0) best = min(best, i);
        }
    }
    #pragma unroll
    for (int o = 32; o; o >>= 1) best = min(best, __shfl_down(best, o));

    if (threadIdx.x == 0) {
        float res = -1.0f;
        if (best != INT_MAX) {
            const int j = jv[(size_t)b * L + best];
            const float gx = s1[((size_t)b * L + j) * 2 + 0];
            const float gy = s1[((size_t)b * L + j) * 2 + 1];
            const float dx = gx - mk1[2 * n + 0];
            const float dy = gy - mk1[2 * n + 1];
            const float pn = sqrtf(dx * dx + dy * dy);
            if (pn < 10.0f) res = pn;
        }
        pnbuf[n] = res;
    }
}

// ---------- finalize: reduce partials, jv validity, pnbuf ----------
__global__ __launch_bounds__(1024) void mc_finalize_kernel(
    const float* __restrict__ partial, const int* __restrict__ jv,
    const float* __restrict__ pnbuf, int M, int N, float binv,
    float* __restrict__ out)
{
    float csum = 0.0f, fsum = 0.0f;
    int vcnt = 0, fcnt = 0;
    for (int i = threadIdx.x; i < M; i += 1024) {
        csum += partial[i];
        vcnt += (jv[i] >= 0) ? 1 : 0;
    }
    for (int i = threadIdx.x; i < N; i += 1024) {
        const float p = pnbuf[i];
        if (p >= 0.0f) { fsum += p; ++fcnt; }
    }
    #pragma unroll
    for (int o = 32; o; o >>= 1) {
        csum += __shfl_down(csum, o);
        vcnt += __shfl_down(vcnt, o);
        fsum += __shfl_down(fsum, o);
        fcnt += __shfl_down(fcnt, o);
    }
    __shared__ float sc[16], sf[16];
    __shared__ int   sv[16], sn[16];
    const int wid = threadIdx.x >> 6, lane = threadIdx.x & 63;
    if (lane == 0) { sc[wid] = csum; sv[wid] = vcnt; sf[wid] = fsum; sn[wid] = fcnt; }
    __syncthreads();
    if (threadIdx.x == 0) {
        float C = 0.0f, F = 0.0f; int V = 0, K = 0;
        const int nw = blockDim.x >> 6;
        for (int w = 0; w < nw; ++w) { C += sc[w]; V += sv[w]; F += sf[w]; K += sn[w]; }
        const float coarse = -C * binv;
        const float fine = (V > 0) ? ((K > 0) ? F / (float)K : 10.0f) : 1e-6f;
        out[0] = coarse + 1000.0f * fine;
        out[1] = coarse;
        out[2] = fine;
    }
}

extern "C" void kernel_launch(void* const* d_in, const int* in_sizes, int n_in,
                              void* d_out, int out_size, void* d_ws, size_t ws_size,
                              hipStream_t stream) {
    const float* cm  = (const float*)d_in[0];  // [B,L,L]
    const float* gt  = (const float*)d_in[1];  // [B,L,L]
    const float* s0  = (const float*)d_in[2];  // [B,L,2]
    const float* s1  = (const float*)d_in[3];  // [B,L,2]
    const float* mk0 = (const float*)d_in[4];  // [N,3]
    const float* mk1 = (const float*)d_in[5];  // [N,2]
    float* out = (float*)d_out;

    const int L = 2 * (in_sizes[0] / in_sizes[2]);
    const int B = in_sizes[2] / (2 * L);
    const int N = in_sizes[4] / 3;
    const int M = B * L;

    float* partial = (float*)d_ws;
    int*   jv      = (int*)((char*)d_ws + (size_t)M * 4);
    float* pnbuf   = (float*)((char*)d_ws + (size_t)M * 8);

    const int cgrid = (M + 3) / 4;   // 4 rows (waves) per 256-thread block
    if (L == 4096) {
        mc_coarse_tpl<4096><<<cgrid, 256, 0, stream>>>(cm, gt, M, partial, jv);
    } else {
        mc_coarse_gen<<<cgrid, 256, 0, stream>>>(cm, gt, L, M, partial, jv);
    }
    mc_fine_kernel<<<N, 64, 0, stream>>>(s0, s1, mk0, mk1, jv, B, L, pnbuf);
    mc_finalize_kernel<<<1, 1024, 0, stream>>>(partial, jv, pnbuf, M, N, 1.0f / (float)B, out);
}